// Round 12
// baseline (264.686 us; speedup 1.0000x reference)
//
#include <hip/hip_runtime.h>

typedef short short8  __attribute__((ext_vector_type(8)));
typedef short short4v __attribute__((ext_vector_type(4)));
typedef float f32x4   __attribute__((ext_vector_type(4)));

#define MFMA_BF16(A,B,C) __builtin_amdgcn_mfma_f32_16x16x32_bf16((A),(B),(C),0,0,0)

__device__ __forceinline__ short bf16bits(float f){
  return (short)__builtin_bit_cast(unsigned short, static_cast<__bf16>(f));
}

// exp(s*0.125 - 8) = 2^(s*0.125*log2e - 8*log2e), one v_fma + v_exp
#define EXP_SCORE(s) __builtin_amdgcn_exp2f(__builtin_fmaf((s), 0.18033688011112042f, -11.541560327111707f))

// ---------------- fused preprocessing ----------------
// blocks [0,220): mask preprocessing  (region_masks -> allowed bits)
// blocks [220,988): K/V repack to bf16, IDENTITY-LANE fragment chunks
// (1KB = 64 lanes x 16B, lane l at offset l*16 -> conflict-free/coalesced).
//   K  chunk (t,f):  lane = Qd*16 + ck  holds K[key=t*16+ck][d=f*32+Qd*8+j]
//   V^T chunk (kc,m): keys PERMUTED by sigma so the score MFMA's C-layout
//     feeds the PV MFMA's B-operand directly (NO P buffer, round 12):
//     score C-layout: lane (Q,c) holds tile keys Q*4+r. PV B-layout: lane
//     (Q,c) k-slots Q*8+j. Choose sigma(Q*8+j) = Q*4+j (j<4), 16+Q*4+j-4
//     (j>=4) and permute V's key dim by sigma (K-scores and V rows use the
//     same key order within each 32-key chunk -> product unchanged).
//     Inverse: for key kkc in chunk: Qv=(kkc>>2)&3, jv=(kkc&3)|((kkc&16)>>2).
__global__ __launch_bounds__(256) void prep_kernel(const float* __restrict__ rm,
                                                   const float* __restrict__ k,
                                                   const float* __restrict__ v,
                                                   const float* __restrict__ rk,
                                                   const float* __restrict__ rv,
                                                   unsigned* __restrict__ allowed,
                                                   unsigned short* __restrict__ Kb,
                                                   unsigned short* __restrict__ VT){
  const int bid = blockIdx.x;
  if (bid < 220){
    int s = bid*256 + threadIdx.x;
    if (s >= 56320) return;
    int t = s / 3520;
    int rem = s - t*3520;
    int i = rem / 80;
    int j = rem - i*80;
    int y = 2*i, x = 2*j;
    bool bin[2];
    #pragma unroll
    for (int r=0;r<2;r++){
      const float* base = rm + (size_t)r*121*88*160;
      float acc;
      if (t == 0){
        const float* p0 = base + (size_t)(0*88 + y)*160 + x;
        acc = 0.25f*(p0[0]+p0[1]+p0[160]+p0[161]);
      } else {
        const float* pa = base + (size_t)((8*t-4)*88 + y)*160 + x;
        const float* pb = base + (size_t)((8*t-3)*88 + y)*160 + x;
        acc = 0.125f*(pa[0]+pa[1]+pa[160]+pa[161] + pb[0]+pb[1]+pb[160]+pb[161]);
      }
      bin[r] = acc > 0.5f;
    }
    unsigned bits = (bin[0]||bin[1]) ? 0u : 1u;
    if (bin[0]) bits |= 2u;
    if (bin[1]) bits |= 4u;
    allowed[s] = bits;
  } else {
    int idx = (bid-220)*256 + threadIdx.x;   // over 3*128*8*64 = 196608
    if (idx >= 3*128*8*64) return;
    int d   = idx & 63;
    int h   = (idx >> 6) & 7;
    int p   = (idx >> 9) & 127;
    int seg = idx >> 16;
    int low = idx & 65535;                   // (p*8+h)*64+d
    float kv_, vv_;
    if (seg == 0){ kv_ = k[low];                          vv_ = v[low]; }
    else         { kv_ = rk[(size_t)(seg-1)*65536 + low]; vv_ = rv[(size_t)(seg-1)*65536 + low]; }
    const int kk = seg*128 + p;              // key index within head, 0..383
    // K: chunk (t=kk>>4, f=d>>5), lane = ((d>>3)&3)*16 + (kk&15), elem j=d&7
    Kb[(size_t)h*24576 + ((kk>>4)*2 + (d>>5))*512
       + ((((d>>3)&3)*16) + (kk&15))*8 + (d&7)] = (unsigned short)bf16bits(kv_);
    // V^T: chunk (kc=kk>>5, m=d>>4), sigma-permuted key slot
    {
      const int kkc = kk & 31;
      const int Qv  = (kkc >> 2) & 3;
      const int jv  = (kkc & 3) | ((kkc & 16) >> 2);
      VT[(size_t)h*24576 + ((kk>>5)*4 + (d>>4))*512
         + (Qv*16 + (d&15))*8 + jv] = (unsigned short)bf16bits(vv_);
    }
  }
}

// ---------------- fused regional+base attention ----------------
// 512 threads (8 waves) per (head, 128-query chunk); one 16-query set per
// wave. K (48KB) staged in LDS; V frags from L2 with pinned single-buffer
// register prefetch (rounds 10-11). ROUND 12: NO P BUFFER. The sigma-
// permuted V layout (see prep) makes each lane's packed exp-scores for a
// tile pair exactly the PV MFMA B-fragment: MFMA -> exp -> cvt -> MFMA,
// fully in-lane. Deletes 36 LDS ops/wave, all P bank conflicts, the P RAW
// latency, and 32KB LDS: Ks-only 48KB -> 3 blocks/CU -> 6 waves/SIMD
// (needs VGPR <= 85; est ~80 = 32 acc + 8 qf + 16 Vpre + temps).
// 12 chunks of 32 keys: chunks 0-3 base -> a0/lb, 4-7 region0 (am1) and
// 8-11 region1 (am2) -> a1/lr. Compile-time acc selection everywhere.
__global__ __launch_bounds__(512)
void attn_kernel(const float* __restrict__ q,
                 const unsigned* __restrict__ allowed,
                 const unsigned short* __restrict__ Kb,
                 const unsigned short* __restrict__ VT,
                 float* __restrict__ out){
  const int h    = blockIdx.y;
  const int wave = threadIdx.x >> 6;
  const int lane = threadIdx.x & 63;
  const int c    = lane & 15;        // query col / fragment row
  const int Q    = lane >> 4;        // quad

  __shared__ __align__(16) char Ks[49152];   // 24 tiles x 2 frags x 1KB

  const int s = blockIdx.x*128 + wave*16 + c;

  // ---- stage K: issue the 6 loads first; q work overlaps the latency
  const char* kg = (const char*)Kb + (size_t)h*49152;
  short8 st0 = *(const short8*)(kg + wave*6144 + 0*1024 + lane*16);
  short8 st1 = *(const short8*)(kg + wave*6144 + 1*1024 + lane*16);
  short8 st2 = *(const short8*)(kg + wave*6144 + 2*1024 + lane*16);
  short8 st3 = *(const short8*)(kg + wave*6144 + 3*1024 + lane*16);
  short8 st4 = *(const short8*)(kg + wave*6144 + 4*1024 + lane*16);
  short8 st5 = *(const short8*)(kg + wave*6144 + 5*1024 + lane*16);

  // ---- q load -> bf16 frags immediately (8 regs live past here)
  const unsigned ab = allowed[s];
  const float* qp = q + ((size_t)s*8 + h)*64 + Q*8;
  f32x4 q0 = *(const f32x4*)(qp);
  f32x4 q1 = *(const f32x4*)(qp+4);
  f32x4 q2 = *(const f32x4*)(qp+32);
  f32x4 q3 = *(const f32x4*)(qp+36);
  short8 f0, f1;
  #pragma unroll
  for (int j=0;j<4;j++){
    f0[j] = bf16bits(q0[j]); f0[4+j] = bf16bits(q1[j]);
    f1[j] = bf16bits(q2[j]); f1[4+j] = bf16bits(q3[j]);
  }

  // ---- K -> LDS (pure linear, conflict-free)
  *(short8*)(Ks + wave*6144 + 0*1024 + lane*16) = st0;
  *(short8*)(Ks + wave*6144 + 1*1024 + lane*16) = st1;
  *(short8*)(Ks + wave*6144 + 2*1024 + lane*16) = st2;
  *(short8*)(Ks + wave*6144 + 3*1024 + lane*16) = st3;
  *(short8*)(Ks + wave*6144 + 4*1024 + lane*16) = st4;
  *(short8*)(Ks + wave*6144 + 5*1024 + lane*16) = st5;

  // ---- identity-lane fragment bases (linear, conflict-free)
  const char* kfb = Ks + lane*16;                                 // + (t*2+f)*1024
  const char* vgf = (const char*)VT + (size_t)h*49152 + lane*16;  // global V frags

  // ---- V prefetch buffer (single, compile-time indexed): chunk kc -> 4 frags
  short8 v0, v1, v2, v3;
#define VLOAD(kc)                                                     \
  v0 = *(const short8*)(vgf + ((kc)*4+0)*1024);                       \
  v1 = *(const short8*)(vgf + ((kc)*4+1)*1024);                       \
  v2 = *(const short8*)(vgf + ((kc)*4+2)*1024);                       \
  v3 = *(const short8*)(vgf + ((kc)*4+3)*1024);                       \
  __builtin_amdgcn_sched_barrier(0);   /* pin: loads may not sink */

// one 32-key chunk: scores for tile pair -> exp -> pf (the PV B-frag,
// thanks to the sigma-permuted V layout) -> 4 PV MFMAs
#define CHUNK(kc, LSUM, AM, ACC)                                      \
  {                                                                   \
    short8 kf0 = *(const short8*)(kfb + ((kc)*4+0)*1024);             \
    short8 kf1 = *(const short8*)(kfb + ((kc)*4+1)*1024);             \
    short8 kf2 = *(const short8*)(kfb + ((kc)*4+2)*1024);             \
    short8 kf3 = *(const short8*)(kfb + ((kc)*4+3)*1024);             \
    f32x4 sA = {0,0,0,0}; sA = MFMA_BF16(kf0,f0,sA); sA = MFMA_BF16(kf1,f1,sA); \
    f32x4 sB = {0,0,0,0}; sB = MFMA_BF16(kf2,f0,sB); sB = MFMA_BF16(kf3,f1,sB); \
    short8 pf;                                                        \
    _Pragma("unroll")                                                 \
    for (int r=0;r<4;r++){                                            \
      float eA = (AM)*EXP_SCORE(sA[r]); LSUM += eA; pf[r]   = bf16bits(eA); \
      float eB = (AM)*EXP_SCORE(sB[r]); LSUM += eB; pf[4+r] = bf16bits(eB); \
    }                                                                 \
    ACC[0] = MFMA_BF16(v0, pf, ACC[0]);                               \
    ACC[1] = MFMA_BF16(v1, pf, ACC[1]);                               \
    ACC[2] = MFMA_BF16(v2, pf, ACC[2]);                               \
    ACC[3] = MFMA_BF16(v3, pf, ACC[3]);                               \
  }

  // chunk-0 V loads before the barrier: drained alongside K staging, free
  VLOAD(0);

  __syncthreads();   // staged K visible to all waves

  const float am1 = (ab>>1)&1u ? 1.f : 0.f;   // region 0 (chunks 4-7)
  const float am2 = (ab>>2)&1u ? 1.f : 0.f;   // region 1 (chunks 8-11)

  float lb=0.f, lr=0.f;
  f32x4 a0[4], a1[4];
  #pragma unroll
  for (int m=0;m<4;m++){ a0[m]=(f32x4){0,0,0,0}; a1[m]=(f32x4){0,0,0,0}; }

  // ---- 12 chunks, fully unrolled; V loads pinned one chunk ahead of use
  CHUNK(0,  lb, 1.0f, a0); VLOAD(1);
  CHUNK(1,  lb, 1.0f, a0); VLOAD(2);
  CHUNK(2,  lb, 1.0f, a0); VLOAD(3);
  CHUNK(3,  lb, 1.0f, a0); VLOAD(4);
  CHUNK(4,  lr, am1,  a1); VLOAD(5);
  CHUNK(5,  lr, am1,  a1); VLOAD(6);
  CHUNK(6,  lr, am1,  a1); VLOAD(7);
  CHUNK(7,  lr, am1,  a1); VLOAD(8);
  CHUNK(8,  lr, am2,  a1); VLOAD(9);
  CHUNK(9,  lr, am2,  a1); VLOAD(10);
  CHUNK(10, lr, am2,  a1); VLOAD(11);
  CHUNK(11, lr, am2,  a1);

  // ---- row-sum reductions (query lives in lane&15; reduce across quads)
  lb += __shfl_xor(lb,16); lb += __shfl_xor(lb,32);
  lr += __shfl_xor(lr,16); lr += __shfl_xor(lr,32);

  const float invb = 0.5f/lb;
  const float lreg = ((ab&1u)? lb : 0.f) + lr;
  const float invr = 0.5f/lreg;
  const float cA   = invb + ((ab&1u)? invr : 0.f);

  // ---- store: lane holds d = m*16 + Q*4 + r for query s (fp32, 16B)
  float* ob = out + (size_t)s*512 + h*64 + Q*4;
  #pragma unroll
  for (int m=0;m<4;m++){
    f32x4 o;
    #pragma unroll
    for (int r=0;r<4;r++) o[r] = a0[m][r]*cA + a1[m][r]*invr;
    *(f32x4*)(ob + m*16) = o;
  }
}

extern "C" void kernel_launch(void* const* d_in, const int* in_sizes, int n_in,
                              void* d_out, int out_size, void* d_ws, size_t ws_size,
                              hipStream_t stream) {
  const float* q  = (const float*)d_in[0];
  const float* k  = (const float*)d_in[1];
  const float* v  = (const float*)d_in[2];
  const float* rk = (const float*)d_in[3];
  const float* rv = (const float*)d_in[4];
  const float* rm = (const float*)d_in[5];
  float* out = (float*)d_out;

  char* ws = (char*)d_ws;
  unsigned*       allowed = (unsigned*)ws;                           // 56320*4   = 225280 B
  unsigned short* Kb      = (unsigned short*)(ws + 225280);          // 8*3*128*64*2 = 393216 B
  unsigned short* VT      = (unsigned short*)(ws + 225280 + 393216); // 393216 B

  prep_kernel<<<988, 256, 0, stream>>>(rm, k, v, rk, rv, allowed, Kb, VT);
  dim3 grid(440, 8);
  attn_kernel<<<grid, 512, 0, stream>>>(q, allowed, Kb, VT, out);
}

// Round 13
// 260.896 us; speedup vs baseline: 1.0145x; 1.0145x over previous
//
#include <hip/hip_runtime.h>

typedef short short8  __attribute__((ext_vector_type(8)));
typedef short short4v __attribute__((ext_vector_type(4)));
typedef float f32x4   __attribute__((ext_vector_type(4)));

#define MFMA_BF16(A,B,C) __builtin_amdgcn_mfma_f32_16x16x32_bf16((A),(B),(C),0,0,0)

__device__ __forceinline__ short bf16bits(float f){
  return (short)__builtin_bit_cast(unsigned short, static_cast<__bf16>(f));
}

// exp(s*0.125 - 8) = exp2(s*0.125*log2e - 8*log2e): one v_fma + v_exp.
// The -8 reference and the region mask are folded into BIAS:
//   BIAS = -11.5416 (allowed)  |  -3e38 (masked: exp2(-3e38) == 0 exactly)
#define EXP_SCORE(s, BIAS) __builtin_amdgcn_exp2f(__builtin_fmaf((s), 0.18033688011112042f, (BIAS)))
#define EXP_C2 (-11.541560327111707f)

// ---------------- fused preprocessing ----------------
// blocks [0,220): mask preprocessing  (region_masks -> allowed bits)
// blocks [220,988): K/V repack to bf16, IDENTITY-LANE fragment chunks
// (1KB = 64 lanes x 16B, lane l at offset l*16 -> conflict-free/coalesced).
//   K  chunk (t,f):  lane = Qd*16 + ck  holds K[key=t*16+ck][d=f*32+Qd*8+j]
//   V^T chunk (kc,m): keys PERMUTED by sigma so the score MFMA's C-layout
//     feeds the PV MFMA's B-operand directly (no P buffer):
//     sigma(Q*8+j) = Q*4+j (j<4), 16+Q*4+(j-4) (j>=4); K-scores and V rows
//     share the key order within each 32-key chunk -> product unchanged.
//     Inverse: for key kkc in chunk: Qv=(kkc>>2)&3, jv=(kkc&3)|((kkc&16)>>2).
__global__ __launch_bounds__(256) void prep_kernel(const float* __restrict__ rm,
                                                   const float* __restrict__ k,
                                                   const float* __restrict__ v,
                                                   const float* __restrict__ rk,
                                                   const float* __restrict__ rv,
                                                   unsigned* __restrict__ allowed,
                                                   unsigned short* __restrict__ Kb,
                                                   unsigned short* __restrict__ VT){
  const int bid = blockIdx.x;
  if (bid < 220){
    int s = bid*256 + threadIdx.x;
    if (s >= 56320) return;
    int t = s / 3520;
    int rem = s - t*3520;
    int i = rem / 80;
    int j = rem - i*80;
    int y = 2*i, x = 2*j;
    bool bin[2];
    #pragma unroll
    for (int r=0;r<2;r++){
      const float* base = rm + (size_t)r*121*88*160;
      float acc;
      if (t == 0){
        const float* p0 = base + (size_t)(0*88 + y)*160 + x;
        acc = 0.25f*(p0[0]+p0[1]+p0[160]+p0[161]);
      } else {
        const float* pa = base + (size_t)((8*t-4)*88 + y)*160 + x;
        const float* pb = base + (size_t)((8*t-3)*88 + y)*160 + x;
        acc = 0.125f*(pa[0]+pa[1]+pa[160]+pa[161] + pb[0]+pb[1]+pb[160]+pb[161]);
      }
      bin[r] = acc > 0.5f;
    }
    unsigned bits = (bin[0]||bin[1]) ? 0u : 1u;
    if (bin[0]) bits |= 2u;
    if (bin[1]) bits |= 4u;
    allowed[s] = bits;
  } else {
    int idx = (bid-220)*256 + threadIdx.x;   // over 3*128*8*64 = 196608
    if (idx >= 3*128*8*64) return;
    int d   = idx & 63;
    int h   = (idx >> 6) & 7;
    int p   = (idx >> 9) & 127;
    int seg = idx >> 16;
    int low = idx & 65535;                   // (p*8+h)*64+d
    float kv_, vv_;
    if (seg == 0){ kv_ = k[low];                          vv_ = v[low]; }
    else         { kv_ = rk[(size_t)(seg-1)*65536 + low]; vv_ = rv[(size_t)(seg-1)*65536 + low]; }
    const int kk = seg*128 + p;              // key index within head, 0..383
    // K: chunk (t=kk>>4, f=d>>5), lane = ((d>>3)&3)*16 + (kk&15), elem j=d&7
    Kb[(size_t)h*24576 + ((kk>>4)*2 + (d>>5))*512
       + ((((d>>3)&3)*16) + (kk&15))*8 + (d&7)] = (unsigned short)bf16bits(kv_);
    // V^T: chunk (kc=kk>>5, m=d>>4), sigma-permuted key slot
    {
      const int kkc = kk & 31;
      const int Qv  = (kkc >> 2) & 3;
      const int jv  = (kkc & 3) | ((kkc & 16) >> 2);
      VT[(size_t)h*24576 + ((kk>>5)*4 + (d>>4))*512
         + (Qv*16 + (d&15))*8 + jv] = (unsigned short)bf16bits(vv_);
    }
  }
}

// ---------------- fused regional+base attention ----------------
// 512 threads (8 waves) per (head, 128-query chunk); one 16-query set per
// wave. K (48KB) staged in LDS; V frags from L2 with pinned single-buffer
// register prefetch; NO P buffer (sigma-permuted V, round 12).
// ROUND 13: round 12's sched_barrier(0) after each VLOAD serialized the
// kernel at chunk granularity (nothing could cross -> VGPR stuck at 64, no
// cross-chunk ILP, full dependency chain exposed per chunk). Replace with
// sched_barrier(0x38F) = allow ALU|VALU|SALU|MFMA|DS|DS_READ|DS_WRITE to
// cross, block only VMEM: V loads stay pinned one chunk ahead, while K
// ds_reads / score MFMAs / exp of chunk i+1 can overlap chunk i's PV —
// the r11 LDS pipeline, now in registers. Also: region mask folded into
// the exp2 bias (-3e38 -> exact 0) removing 8 VALU muls per chunk.
__global__ __launch_bounds__(512)
void attn_kernel(const float* __restrict__ q,
                 const unsigned* __restrict__ allowed,
                 const unsigned short* __restrict__ Kb,
                 const unsigned short* __restrict__ VT,
                 float* __restrict__ out){
  const int h    = blockIdx.y;
  const int wave = threadIdx.x >> 6;
  const int lane = threadIdx.x & 63;
  const int c    = lane & 15;        // query col / fragment row
  const int Q    = lane >> 4;        // quad

  __shared__ __align__(16) char Ks[49152];   // 24 tiles x 2 frags x 1KB

  const int s = blockIdx.x*128 + wave*16 + c;

  // ---- stage K: issue the 6 loads first; q work overlaps the latency
  const char* kg = (const char*)Kb + (size_t)h*49152;
  short8 st0 = *(const short8*)(kg + wave*6144 + 0*1024 + lane*16);
  short8 st1 = *(const short8*)(kg + wave*6144 + 1*1024 + lane*16);
  short8 st2 = *(const short8*)(kg + wave*6144 + 2*1024 + lane*16);
  short8 st3 = *(const short8*)(kg + wave*6144 + 3*1024 + lane*16);
  short8 st4 = *(const short8*)(kg + wave*6144 + 4*1024 + lane*16);
  short8 st5 = *(const short8*)(kg + wave*6144 + 5*1024 + lane*16);

  // ---- q load -> bf16 frags immediately (8 regs live past here)
  const unsigned ab = allowed[s];
  const float* qp = q + ((size_t)s*8 + h)*64 + Q*8;
  f32x4 q0 = *(const f32x4*)(qp);
  f32x4 q1 = *(const f32x4*)(qp+4);
  f32x4 q2 = *(const f32x4*)(qp+32);
  f32x4 q3 = *(const f32x4*)(qp+36);
  short8 f0, f1;
  #pragma unroll
  for (int j=0;j<4;j++){
    f0[j] = bf16bits(q0[j]); f0[4+j] = bf16bits(q1[j]);
    f1[j] = bf16bits(q2[j]); f1[4+j] = bf16bits(q3[j]);
  }

  // ---- K -> LDS (pure linear, conflict-free)
  *(short8*)(Ks + wave*6144 + 0*1024 + lane*16) = st0;
  *(short8*)(Ks + wave*6144 + 1*1024 + lane*16) = st1;
  *(short8*)(Ks + wave*6144 + 2*1024 + lane*16) = st2;
  *(short8*)(Ks + wave*6144 + 3*1024 + lane*16) = st3;
  *(short8*)(Ks + wave*6144 + 4*1024 + lane*16) = st4;
  *(short8*)(Ks + wave*6144 + 5*1024 + lane*16) = st5;

  // ---- identity-lane fragment bases (linear, conflict-free)
  const char* kfb = Ks + lane*16;                                 // + (t*2+f)*1024
  const char* vgf = (const char*)VT + (size_t)h*49152 + lane*16;  // global V frags

  // ---- V prefetch buffer (single, compile-time indexed): chunk kc -> 4 frags
  short8 v0, v1, v2, v3;
#define VLOAD(kc)                                                     \
  v0 = *(const short8*)(vgf + ((kc)*4+0)*1024);                       \
  v1 = *(const short8*)(vgf + ((kc)*4+1)*1024);                       \
  v2 = *(const short8*)(vgf + ((kc)*4+2)*1024);                       \
  v3 = *(const short8*)(vgf + ((kc)*4+3)*1024);                       \
  /* pin VMEM issue order; let VALU/MFMA/DS flow across for ILP */    \
  __builtin_amdgcn_sched_barrier(0x38F);

// one 32-key chunk: scores for tile pair -> exp2(fma) with mask folded in
// the bias -> pf (the PV B-frag, thanks to sigma-permuted V) -> 4 PV MFMAs
#define CHUNK(kc, LSUM, BIAS, ACC)                                    \
  {                                                                   \
    short8 kf0 = *(const short8*)(kfb + ((kc)*4+0)*1024);             \
    short8 kf1 = *(const short8*)(kfb + ((kc)*4+1)*1024);             \
    short8 kf2 = *(const short8*)(kfb + ((kc)*4+2)*1024);             \
    short8 kf3 = *(const short8*)(kfb + ((kc)*4+3)*1024);             \
    f32x4 sA = {0,0,0,0}; sA = MFMA_BF16(kf0,f0,sA); sA = MFMA_BF16(kf1,f1,sA); \
    f32x4 sB = {0,0,0,0}; sB = MFMA_BF16(kf2,f0,sB); sB = MFMA_BF16(kf3,f1,sB); \
    short8 pf;                                                        \
    _Pragma("unroll")                                                 \
    for (int r=0;r<4;r++){                                            \
      float eA = EXP_SCORE(sA[r], BIAS); LSUM += eA; pf[r]   = bf16bits(eA); \
      float eB = EXP_SCORE(sB[r], BIAS); LSUM += eB; pf[4+r] = bf16bits(eB); \
    }                                                                 \
    ACC[0] = MFMA_BF16(v0, pf, ACC[0]);                               \
    ACC[1] = MFMA_BF16(v1, pf, ACC[1]);                               \
    ACC[2] = MFMA_BF16(v2, pf, ACC[2]);                               \
    ACC[3] = MFMA_BF16(v3, pf, ACC[3]);                               \
  }

  // chunk-0 V loads before the barrier: drained alongside K staging, free
  VLOAD(0);

  __syncthreads();   // staged K visible to all waves

  const float bias1 = ((ab>>1)&1u) ? EXP_C2 : -3.0e38f;  // region 0 (chunks 4-7)
  const float bias2 = ((ab>>2)&1u) ? EXP_C2 : -3.0e38f;  // region 1 (chunks 8-11)

  float lb=0.f, lr=0.f;
  f32x4 a0[4], a1[4];
  #pragma unroll
  for (int m=0;m<4;m++){ a0[m]=(f32x4){0,0,0,0}; a1[m]=(f32x4){0,0,0,0}; }

  // ---- 12 chunks, fully unrolled; V loads pinned one chunk ahead of use
  CHUNK(0,  lb, EXP_C2, a0); VLOAD(1);
  CHUNK(1,  lb, EXP_C2, a0); VLOAD(2);
  CHUNK(2,  lb, EXP_C2, a0); VLOAD(3);
  CHUNK(3,  lb, EXP_C2, a0); VLOAD(4);
  CHUNK(4,  lr, bias1,  a1); VLOAD(5);
  CHUNK(5,  lr, bias1,  a1); VLOAD(6);
  CHUNK(6,  lr, bias1,  a1); VLOAD(7);
  CHUNK(7,  lr, bias1,  a1); VLOAD(8);
  CHUNK(8,  lr, bias2,  a1); VLOAD(9);
  CHUNK(9,  lr, bias2,  a1); VLOAD(10);
  CHUNK(10, lr, bias2,  a1); VLOAD(11);
  CHUNK(11, lr, bias2,  a1);

  // ---- row-sum reductions (query lives in lane&15; reduce across quads)
  lb += __shfl_xor(lb,16); lb += __shfl_xor(lb,32);
  lr += __shfl_xor(lr,16); lr += __shfl_xor(lr,32);

  const float invb = 0.5f/lb;
  const float lreg = ((ab&1u)? lb : 0.f) + lr;
  const float invr = 0.5f/lreg;
  const float cA   = invb + ((ab&1u)? invr : 0.f);

  // ---- store: lane holds d = m*16 + Q*4 + r for query s (fp32, 16B)
  float* ob = out + (size_t)s*512 + h*64 + Q*4;
  #pragma unroll
  for (int m=0;m<4;m++){
    f32x4 o;
    #pragma unroll
    for (int r=0;r<4;r++) o[r] = a0[m][r]*cA + a1[m][r]*invr;
    *(f32x4*)(ob + m*16) = o;
  }
}

extern "C" void kernel_launch(void* const* d_in, const int* in_sizes, int n_in,
                              void* d_out, int out_size, void* d_ws, size_t ws_size,
                              hipStream_t stream) {
  const float* q  = (const float*)d_in[0];
  const float* k  = (const float*)d_in[1];
  const float* v  = (const float*)d_in[2];
  const float* rk = (const float*)d_in[3];
  const float* rv = (const float*)d_in[4];
  const float* rm = (const float*)d_in[5];
  float* out = (float*)d_out;

  char* ws = (char*)d_ws;
  unsigned*       allowed = (unsigned*)ws;                           // 56320*4   = 225280 B
  unsigned short* Kb      = (unsigned short*)(ws + 225280);          // 8*3*128*64*2 = 393216 B
  unsigned short* VT      = (unsigned short*)(ws + 225280 + 393216); // 393216 B

  prep_kernel<<<988, 256, 0, stream>>>(rm, k, v, rk, rv, allowed, Kb, VT);
  dim3 grid(440, 8);
  attn_kernel<<<grid, 512, 0, stream>>>(q, allowed, Kb, VT, out);
}